// Round 4
// baseline (1780.745 us; speedup 1.0000x reference)
//
#include <hip/hip_runtime.h>
#include <hip/hip_bf16.h>

// StructuredLinear (toeplitz_like, Stein displacement): y = x @ W
//   W[n,m] = p[(n-m)%N][m] - 0.5*c[(n-m)%N]
//   p[d][m] = sum_{j<=m} t[d][j],  c[d] = p[d][N-1]
//   t[d][j] = sum_r G[(d+j)%N][r] * H[j][r]
// N=4096, R=4, B=8192.
// Pipeline: build_T (fp32) -> gather W^T as bf16 hi/lo planes -> split x into
// bf16 hi/lo planes -> split-bf16 MFMA GEMM (x_hi*W_hi + x_hi*W_lo + x_lo*W_hi,
// fp32 accum).  GEMM: 128x128 tile, BK=32, 2-phase LDS double-buffer,
// chunk-major LDS (conflict-free ds_read_b128), XCD-swizzled blocks, setprio.

constexpr int N = 4096;
constexpr int BATCH = 8192;
constexpr int BK = 32;
constexpr int NT = N / BK;  // 128 K-steps

typedef __attribute__((ext_vector_type(8))) short short8;
typedef __attribute__((ext_vector_type(4))) float f32x4;

// ---------------------------------------------------------------------------
// Kernel 1: per-diagonal prefix scan.  One workgroup per d (4096 blocks).
// T[d][m] = inclusive_prefix(t[d][.])[m] - 0.5 * total
// Wave-shuffle scan: 1 barrier instead of 16.
// ---------------------------------------------------------------------------
__global__ __launch_bounds__(256) void build_T_kernel(const float* __restrict__ G,
                                                      const float* __restrict__ H,
                                                      float* __restrict__ T) {
    const int d = blockIdx.x;
    const int tid = threadIdx.x;
    const int lane = tid & 63;
    const int wid = tid >> 6;
    const int j0 = tid * 16;

    float pref[16];
    float s = 0.f;
#pragma unroll
    for (int i = 0; i < 16; ++i) {
        const int j = j0 + i;
        const float4 g4 = *reinterpret_cast<const float4*>(G + (size_t)((d + j) & (N - 1)) * 4);
        const float4 h4 = *reinterpret_cast<const float4*>(H + (size_t)j * 4);
        s += g4.x * h4.x + g4.y * h4.y + g4.z * h4.z + g4.w * h4.w;
        pref[i] = s;  // inclusive within this thread's chunk
    }

    // inclusive scan of per-thread sums within the wave
    float v = s;
#pragma unroll
    for (int off = 1; off < 64; off <<= 1) {
        const float u = __shfl_up(v, off, 64);
        if (lane >= off) v += u;
    }
    __shared__ float wsum[4];
    if (lane == 63) wsum[wid] = v;
    __syncthreads();
    const float w0 = wsum[0], w1 = wsum[1], w2 = wsum[2], w3 = wsum[3];
    const float total = w0 + w1 + w2 + w3;
    float wpref = 0.f;
    if (wid > 0) wpref += w0;
    if (wid > 1) wpref += w1;
    if (wid > 2) wpref += w2;
    const float excl = wpref + (v - s);  // exclusive prefix before this thread
    const float halfc = 0.5f * total;

    float* out = T + (size_t)d * N + j0;
#pragma unroll
    for (int i = 0; i < 16; ++i) out[i] = excl + pref[i] - halfc;
}

// ---------------------------------------------------------------------------
// Kernel 2a (bf16 path): gather W^T into bf16 hi/lo planes.
// Wt[m][n] = W[n][m] = T[(n-m)&(N-1)][m].  64x64 (m,n) tile per block.
// Vectorized short8 stores (16B/lane).
// ---------------------------------------------------------------------------
__global__ __launch_bounds__(256) void gather_Wt_bf16_kernel(const float* __restrict__ T,
                                                             __hip_bfloat16* __restrict__ Wh,
                                                             __hip_bfloat16* __restrict__ Wl) {
    __shared__ float tile[128][65];
    const int n0 = blockIdx.x * 64;
    const int m0 = blockIdx.y * 64;
    const int d0 = (n0 - m0 - 63) & (N - 1);
    const int t = threadIdx.x;

#pragma unroll
    for (int i = 0; i < 32; ++i) {
        const int flat = t + i * 256;   // 0..8191
        const int row = flat >> 6;      // d-local 0..127
        const int col = flat & 63;      // m-local
        tile[row][col] = T[(size_t)((d0 + row) & (N - 1)) * N + m0 + col];
    }
    __syncthreads();
#pragma unroll
    for (int i = 0; i < 2; ++i) {
        const int lm = (t >> 3) + i * 32;   // m-local 0..63 (row of Wt)
        const int ln0 = (t & 7) * 8;        // n-local start
        short8 hv, lv;
#pragma unroll
        for (int e = 0; e < 8; ++e) {
            const float w = tile[ln0 + e - lm + 63][lm];
            const __hip_bfloat16 h = __float2bfloat16(w);
            const __hip_bfloat16 l = __float2bfloat16(w - __bfloat162float(h));
            hv[e] = *reinterpret_cast<const short*>(&h);
            lv[e] = *reinterpret_cast<const short*>(&l);
        }
        const size_t idx = (size_t)(m0 + lm) * N + n0 + ln0;
        *reinterpret_cast<short8*>(reinterpret_cast<short*>(Wh) + idx) = hv;
        *reinterpret_cast<short8*>(reinterpret_cast<short*>(Wl) + idx) = lv;
    }
}

// ---------------------------------------------------------------------------
// Kernel 2b (fp32 fallback): gather W (row-major [n][m]) in fp32.
// ---------------------------------------------------------------------------
__global__ __launch_bounds__(256) void gather_W_kernel(const float* __restrict__ T,
                                                       float* __restrict__ W) {
    __shared__ float tile[128][64];
    const int m0 = blockIdx.x * 64;
    const int n0 = blockIdx.y * 64;
    const int d0 = (n0 - m0 - 63) & (N - 1);
    const int t = threadIdx.x;

#pragma unroll
    for (int i = 0; i < 32; ++i) {
        const int flat = t + i * 256;
        const int row = flat >> 6;
        const int col = flat & 63;
        tile[row][col] = T[(size_t)((d0 + row) & (N - 1)) * N + m0 + col];
    }
    __syncthreads();
#pragma unroll
    for (int i = 0; i < 16; ++i) {
        const int flat = t + i * 256;
        const int ln = flat >> 6;
        const int lm = flat & 63;
        W[(size_t)(n0 + ln) * N + m0 + lm] = tile[ln - lm + 63][lm];
    }
}

// ---------------------------------------------------------------------------
// Kernel 3: split x (fp32) into bf16 hi/lo planes.
// ---------------------------------------------------------------------------
__global__ __launch_bounds__(256) void split_x_kernel(const float* __restrict__ x,
                                                      __hip_bfloat16* __restrict__ xh,
                                                      __hip_bfloat16* __restrict__ xl) {
    const long long total8 = (long long)BATCH * N / 8;
    for (long long i = (long long)blockIdx.x * 256 + threadIdx.x; i < total8;
         i += (long long)gridDim.x * 256) {
        const float4 a = reinterpret_cast<const float4*>(x)[2 * i];
        const float4 b = reinterpret_cast<const float4*>(x)[2 * i + 1];
        const float v[8] = {a.x, a.y, a.z, a.w, b.x, b.y, b.z, b.w};
        short8 hv, lv;
#pragma unroll
        for (int j = 0; j < 8; ++j) {
            __hip_bfloat16 h = __float2bfloat16(v[j]);
            __hip_bfloat16 l = __float2bfloat16(v[j] - __bfloat162float(h));
            hv[j] = *reinterpret_cast<short*>(&h);
            lv[j] = *reinterpret_cast<short*>(&l);
        }
        *reinterpret_cast<short8*>(reinterpret_cast<short*>(xh) + i * 8) = hv;
        *reinterpret_cast<short8*>(reinterpret_cast<short*>(xl) + i * 8) = lv;
    }
}

// ---------------------------------------------------------------------------
// Kernel 4: split-bf16 MFMA GEMM, 2-phase double-buffered.
// LDS per buffer: 4 planes (Ah,Al,Bh,Bl) x 512 chunks x 16B, chunk-major:
//   plane[chunk][row][8 shorts], chunk = k-subblock (8 shorts), row = tile row.
// Fragment read (lane = lk*16+lr, frag q): addr = (lk*128 + warpRow + q*16+lr)*16B
//   -> lane-contiguous 16B reads, conflict-free (2-way aliasing only).
// ---------------------------------------------------------------------------
__device__ inline void gll16(const void* g, void* l) {
    __builtin_amdgcn_global_load_lds(
        (const __attribute__((address_space(1))) void*)g,
        (__attribute__((address_space(3))) void*)l, 16, 0, 0);
}

__device__ inline void stage_tile(const short* __restrict__ xh, const short* __restrict__ xl,
                                  const short* __restrict__ wh, const short* __restrict__ wl,
                                  int bm0, int bn0, int k0, short* buf) {
    const int t = threadIdx.x;
#pragma unroll
    for (int i = 0; i < 2; ++i) {
        const int f = t + i * 256;      // chunk id 0..511
        const int chunk = f >> 7;       // k-subblock 0..3
        const int row = f & 127;        // tile row
        const size_t ga = (size_t)(bm0 + row) * N + k0 + chunk * 8;
        const size_t gb = (size_t)(bn0 + row) * N + k0 + chunk * 8;
        gll16(xh + ga, (char*)buf + 0 * 8192 + f * 16);
        gll16(xl + ga, (char*)buf + 1 * 8192 + f * 16);
        gll16(wh + gb, (char*)buf + 2 * 8192 + f * 16);
        gll16(wl + gb, (char*)buf + 3 * 8192 + f * 16);
    }
}

__device__ inline void compute_tile(const short* buf, f32x4 acc[4][4],
                                    int wm, int wn, int lr, int lk) {
    short8 ah[4], al[4], bh[4], bl[4];
#pragma unroll
    for (int q = 0; q < 4; ++q) {
        const int ar = lk * 128 + wm * 64 + q * 16 + lr;  // chunk-major index
        const int br = lk * 128 + wn * 64 + q * 16 + lr;
        ah[q] = *reinterpret_cast<const short8*>(buf + 0 * 4096 + ar * 8);
        al[q] = *reinterpret_cast<const short8*>(buf + 1 * 4096 + ar * 8);
        bh[q] = *reinterpret_cast<const short8*>(buf + 2 * 4096 + br * 8);
        bl[q] = *reinterpret_cast<const short8*>(buf + 3 * 4096 + br * 8);
    }
    __builtin_amdgcn_s_setprio(1);
#pragma unroll
    for (int mf = 0; mf < 4; ++mf)
#pragma unroll
        for (int nf = 0; nf < 4; ++nf) {
            acc[mf][nf] = __builtin_amdgcn_mfma_f32_16x16x32_bf16(ah[mf], bh[nf], acc[mf][nf], 0, 0, 0);
            acc[mf][nf] = __builtin_amdgcn_mfma_f32_16x16x32_bf16(ah[mf], bl[nf], acc[mf][nf], 0, 0, 0);
            acc[mf][nf] = __builtin_amdgcn_mfma_f32_16x16x32_bf16(al[mf], bh[nf], acc[mf][nf], 0, 0, 0);
        }
    __builtin_amdgcn_s_setprio(0);
}

__global__ __launch_bounds__(256) void gemm_bf16_split_kernel(
    const short* __restrict__ xh, const short* __restrict__ xl,
    const short* __restrict__ wh, const short* __restrict__ wl,
    float* __restrict__ C) {
    __shared__ short lds0[4 * 4096];  // buffer 0: 4 planes x 8KB = 32KB
    __shared__ short lds1[4 * 4096];  // buffer 1

    // XCD-aware bijective swizzle: 2048 blocks, 8 XCDs, 256 blocks/XCD chunk.
    const int wgid = blockIdx.x;
    const int swz = (wgid & 7) * 256 + (wgid >> 3);
    const int bn0 = (swz & 31) * 128;   // 32 n-blocks (fast within XCD chunk)
    const int bm0 = (swz >> 5) * 128;   // 64 m-blocks

    const int t = threadIdx.x;
    const int lane = t & 63;
    const int w = t >> 6;
    const int wm = w >> 1, wn = w & 1;  // 2x2 wave grid, 64x64 per wave
    const int lr = lane & 15;           // fragment row/col
    const int lk = lane >> 4;           // k-slice group 0..3

    f32x4 acc[4][4];
    const f32x4 zero = {0.f, 0.f, 0.f, 0.f};
#pragma unroll
    for (int i = 0; i < 4; ++i)
#pragma unroll
        for (int j = 0; j < 4; ++j) acc[i][j] = zero;

    stage_tile(xh, xl, wh, wl, bm0, bn0, 0, lds0);
    __syncthreads();

    for (int kt = 0; kt < NT; kt += 2) {
        // even: compute lds0, prefetch (kt+1) into lds1
        stage_tile(xh, xl, wh, wl, bm0, bn0, (kt + 1) * BK, lds1);
        compute_tile(lds0, acc, wm, wn, lr, lk);
        __syncthreads();  // drains vmcnt (lds1 ready) + all reads of lds0 done
        // odd: compute lds1, prefetch (kt+2) into lds0
        if (kt + 2 < NT) stage_tile(xh, xl, wh, wl, bm0, bn0, (kt + 2) * BK, lds0);
        compute_tile(lds1, acc, wm, wn, lr, lk);
        __syncthreads();
    }

    // C/D layout (m89-verified): col = lane&15, row = (lane>>4)*4 + reg
#pragma unroll
    for (int mf = 0; mf < 4; ++mf)
#pragma unroll
        for (int nf = 0; nf < 4; ++nf)
#pragma unroll
            for (int r = 0; r < 4; ++r)
                C[(size_t)(bm0 + wm * 64 + mf * 16 + lk * 4 + r) * N +
                  bn0 + wn * 64 + nf * 16 + lr] = acc[mf][nf][r];
}

// ---------------------------------------------------------------------------
// Kernel 5 (fp32 fallback GEMM), round-0 version.
// ---------------------------------------------------------------------------
__global__ __launch_bounds__(256) void gemm_f32_kernel(const float* __restrict__ A,
                                                       const float* __restrict__ B,
                                                       float* __restrict__ C) {
    __shared__ float As[16][132];
    __shared__ float Bs[16][128];

    const int t = threadIdx.x;
    const int bn0 = blockIdx.x * 128;
    const int bm0 = blockIdx.y * 128;
    const int tx = t & 15;
    const int ty = t >> 4;

    float acc[8][8] = {};

    for (int k0 = 0; k0 < N; k0 += 16) {
#pragma unroll
        for (int i = 0; i < 2; ++i) {
            const int flat4 = t + i * 256;
            const int r = flat4 >> 2;
            const int q = flat4 & 3;
            const float4 av =
                *reinterpret_cast<const float4*>(A + (size_t)(bm0 + r) * N + k0 + q * 4);
            As[q * 4 + 0][r] = av.x;
            As[q * 4 + 1][r] = av.y;
            As[q * 4 + 2][r] = av.z;
            As[q * 4 + 3][r] = av.w;
            const int rb = flat4 >> 5;
            const int qb = flat4 & 31;
            *reinterpret_cast<float4*>(&Bs[rb][qb * 4]) =
                *reinterpret_cast<const float4*>(B + (size_t)(k0 + rb) * N + bn0 + qb * 4);
        }
        __syncthreads();
#pragma unroll
        for (int k = 0; k < 16; ++k) {
            float a[8], b[8];
            *reinterpret_cast<float4*>(a)     = *reinterpret_cast<const float4*>(&As[k][ty * 8]);
            *reinterpret_cast<float4*>(a + 4) = *reinterpret_cast<const float4*>(&As[k][ty * 8 + 4]);
            *reinterpret_cast<float4*>(b)     = *reinterpret_cast<const float4*>(&Bs[k][tx * 8]);
            *reinterpret_cast<float4*>(b + 4) = *reinterpret_cast<const float4*>(&Bs[k][tx * 8 + 4]);
#pragma unroll
            for (int e = 0; e < 8; ++e)
#pragma unroll
                for (int f = 0; f < 8; ++f) acc[e][f] += a[e] * b[f];
        }
        __syncthreads();
    }

#pragma unroll
    for (int e = 0; e < 8; ++e) {
        float* crow = C + (size_t)(bm0 + ty * 8 + e) * N + bn0 + tx * 8;
        *reinterpret_cast<float4*>(crow)     = *reinterpret_cast<const float4*>(&acc[0] + e * 8);
        *reinterpret_cast<float4*>(crow + 4) = *reinterpret_cast<const float4*>(&acc[0] + e * 8 + 4);
    }
}

// ---------------------------------------------------------------------------
extern "C" void kernel_launch(void* const* d_in, const int* in_sizes, int n_in,
                              void* d_out, int out_size, void* d_ws, size_t ws_size,
                              hipStream_t stream) {
    const float* x = (const float*)d_in[0];  // (8192, 4096)
    const float* G = (const float*)d_in[1];  // (4096, 4)
    const float* H = (const float*)d_in[2];  // (4096, 4)
    float* out = (float*)d_out;              // (8192, 4096)

    char* ws = (char*)d_ws;
    const size_t SZ_T  = (size_t)N * N * sizeof(float);          // 64 MiB
    const size_t SZ_Wp = (size_t)N * N * 2;                      // 32 MiB bf16 plane
    const size_t SZ_Xp = (size_t)BATCH * N * 2;                  // 64 MiB bf16 plane

    float* T = nullptr;
    __hip_bfloat16 *Wh = nullptr, *Wl = nullptr, *Xh = nullptr, *Xl = nullptr;
    bool bf16_path = false;

    if (ws_size >= SZ_T + 2 * SZ_Wp + 2 * SZ_Xp) {               // 256 MiB
        T  = (float*)ws;
        Wh = (__hip_bfloat16*)(ws + SZ_T);
        Wl = (__hip_bfloat16*)(ws + SZ_T + SZ_Wp);
        Xh = (__hip_bfloat16*)(ws + SZ_T + 2 * SZ_Wp);
        Xl = (__hip_bfloat16*)(ws + SZ_T + 2 * SZ_Wp + SZ_Xp);
        bf16_path = true;
    } else if (ws_size >= 2 * SZ_Wp + 2 * SZ_Xp) {               // 192 MiB
        T  = (float*)d_out;  // consumed before the GEMM overwrites d_out
        Wh = (__hip_bfloat16*)ws;
        Wl = (__hip_bfloat16*)(ws + SZ_Wp);
        Xh = (__hip_bfloat16*)(ws + 2 * SZ_Wp);
        Xl = (__hip_bfloat16*)(ws + 2 * SZ_Wp + SZ_Xp);
        bf16_path = true;
    }

    if (bf16_path) {
        build_T_kernel<<<dim3(N), dim3(256), 0, stream>>>(G, H, T);
        gather_Wt_bf16_kernel<<<dim3(N / 64, N / 64), dim3(256), 0, stream>>>(T, Wh, Wl);
        split_x_kernel<<<dim3(2048), dim3(256), 0, stream>>>(x, Xh, Xl);
        gemm_bf16_split_kernel<<<dim3(2048), dim3(256), 0, stream>>>(
            (const short*)Xh, (const short*)Xl, (const short*)Wh, (const short*)Wl, out);
    } else {
        // fp32 fallback: T in d_out (overwritten by GEMM afterwards), W in ws.
        float* Tf = (float*)d_out;
        float* W  = (float*)ws;
        build_T_kernel<<<dim3(N), dim3(256), 0, stream>>>(G, H, Tf);
        gather_W_kernel<<<dim3(N / 64, N / 64), dim3(256), 0, stream>>>(Tf, W);
        gemm_f32_kernel<<<dim3(N / 128, BATCH / 128), dim3(256), 0, stream>>>(x, W, out);
    }
}

// Round 6
// 898.235 us; speedup vs baseline: 1.9825x; 1.9825x over previous
//
#include <hip/hip_runtime.h>
#include <hip/hip_bf16.h>

// StructuredLinear (toeplitz_like, Stein displacement): y = x @ W
//   W[n,m] = T[(n-m)%N][m],  T[d][m] = p[d][m] - 0.5*c[d]
//   p[d][m] = sum_{j<=m} t[d][j],  c[d] = p[d][N-1]
//   t[d][j] = sum_r G[(d+j)%N][r] * H[j][r]
// N=4096, R=4, B=8192.
// Pipeline: build_T (fp32) -> gather W^T as fp16 -> cast x to fp16 ->
// single fp16 MFMA GEMM (fp32 accum).  GEMM: 128x128 tile, BK=32, 1-phase
// 2-barrier K-loop (m97 structure: implicit wave-overlap, >=4 blocks/CU),
// chunk-major LDS (0 bank conflicts, measured r4), 2D grid n-fast (96 MB
// concurrent working set < L3; r4's 1D swizzle thrashed L3).

constexpr int N = 4096;
constexpr int BATCH = 8192;
constexpr int BK = 32;
constexpr int NT = N / BK;  // 128 K-steps

typedef _Float16 f16;
typedef __attribute__((ext_vector_type(8))) f16 half8;
typedef __attribute__((ext_vector_type(4))) float f32x4;

// ---------------------------------------------------------------------------
// Kernel 1: per-diagonal prefix scan.  One workgroup per d (4096 blocks).
// ---------------------------------------------------------------------------
__global__ __launch_bounds__(256) void build_T_kernel(const float* __restrict__ G,
                                                      const float* __restrict__ H,
                                                      float* __restrict__ T) {
    const int d = blockIdx.x;
    const int tid = threadIdx.x;
    const int lane = tid & 63;
    const int wid = tid >> 6;
    const int j0 = tid * 16;

    float pref[16];
    float s = 0.f;
#pragma unroll
    for (int i = 0; i < 16; ++i) {
        const int j = j0 + i;
        const float4 g4 = *reinterpret_cast<const float4*>(G + (size_t)((d + j) & (N - 1)) * 4);
        const float4 h4 = *reinterpret_cast<const float4*>(H + (size_t)j * 4);
        s += g4.x * h4.x + g4.y * h4.y + g4.z * h4.z + g4.w * h4.w;
        pref[i] = s;  // inclusive within this thread's chunk
    }

    float v = s;  // wave-inclusive scan of per-thread sums
#pragma unroll
    for (int off = 1; off < 64; off <<= 1) {
        const float u = __shfl_up(v, off, 64);
        if (lane >= off) v += u;
    }
    __shared__ float wsum[4];
    if (lane == 63) wsum[wid] = v;
    __syncthreads();
    const float w0 = wsum[0], w1 = wsum[1], w2 = wsum[2], w3 = wsum[3];
    const float total = w0 + w1 + w2 + w3;
    float wpref = 0.f;
    if (wid > 0) wpref += w0;
    if (wid > 1) wpref += w1;
    if (wid > 2) wpref += w2;
    const float excl = wpref + (v - s);
    const float halfc = 0.5f * total;

    float* out = T + (size_t)d * N + j0;
#pragma unroll
    for (int i = 0; i < 16; ++i) out[i] = excl + pref[i] - halfc;
}

// ---------------------------------------------------------------------------
// Kernel 2a: gather W^T as fp16.  Wt[m][n] = W[n][m] = T[(n-m)&(N-1)][m].
// Wt row = output dim m, Wt col = contraction dim n (k-contiguous for GEMM).
// ---------------------------------------------------------------------------
__global__ __launch_bounds__(256) void gather_Wt_f16_kernel(const float* __restrict__ T,
                                                            f16* __restrict__ Wt) {
    __shared__ float tile[128][65];
    const int n0 = blockIdx.x * 64;
    const int m0 = blockIdx.y * 64;
    const int d0 = (n0 - m0 - 63) & (N - 1);
    const int t = threadIdx.x;

#pragma unroll
    for (int i = 0; i < 32; ++i) {
        const int flat = t + i * 256;   // 0..8191
        const int row = flat >> 6;      // d-local 0..127
        const int col = flat & 63;      // m-local
        tile[row][col] = T[(size_t)((d0 + row) & (N - 1)) * N + m0 + col];
    }
    __syncthreads();
#pragma unroll
    for (int i = 0; i < 2; ++i) {
        const int lm = (t >> 3) + i * 32;   // m-local (row of Wt)
        const int ln0 = (t & 7) * 8;        // n-local start (fast -> coalesced)
        half8 v;
#pragma unroll
        for (int e = 0; e < 8; ++e) v[e] = (f16)tile[ln0 + e - lm + 63][lm];
        *reinterpret_cast<half8*>(Wt + (size_t)(m0 + lm) * N + n0 + ln0) = v;
    }
}

// ---------------------------------------------------------------------------
// Kernel 2b (fp32 fallback): gather W (row-major [n][m]) in fp32.
// ---------------------------------------------------------------------------
__global__ __launch_bounds__(256) void gather_W_kernel(const float* __restrict__ T,
                                                       float* __restrict__ W) {
    __shared__ float tile[128][64];
    const int m0 = blockIdx.x * 64;
    const int n0 = blockIdx.y * 64;
    const int d0 = (n0 - m0 - 63) & (N - 1);
    const int t = threadIdx.x;

#pragma unroll
    for (int i = 0; i < 32; ++i) {
        const int flat = t + i * 256;
        const int row = flat >> 6;
        const int col = flat & 63;
        tile[row][col] = T[(size_t)((d0 + row) & (N - 1)) * N + m0 + col];
    }
    __syncthreads();
#pragma unroll
    for (int i = 0; i < 16; ++i) {
        const int flat = t + i * 256;
        const int ln = flat >> 6;
        const int lm = flat & 63;
        W[(size_t)(n0 + ln) * N + m0 + lm] = tile[ln - lm + 63][lm];
    }
}

// ---------------------------------------------------------------------------
// Kernel 3: cast x (fp32) to fp16.
// ---------------------------------------------------------------------------
__global__ __launch_bounds__(256) void cast_x_f16_kernel(const float* __restrict__ x,
                                                         f16* __restrict__ xh) {
    const long long total8 = (long long)BATCH * N / 8;
    for (long long i = (long long)blockIdx.x * 256 + threadIdx.x; i < total8;
         i += (long long)gridDim.x * 256) {
        const float4 a = reinterpret_cast<const float4*>(x)[2 * i];
        const float4 b = reinterpret_cast<const float4*>(x)[2 * i + 1];
        half8 v;
        v[0] = (f16)a.x; v[1] = (f16)a.y; v[2] = (f16)a.z; v[3] = (f16)a.w;
        v[4] = (f16)b.x; v[5] = (f16)b.y; v[6] = (f16)b.z; v[7] = (f16)b.w;
        *reinterpret_cast<half8*>(xh + i * 8) = v;
    }
}

// ---------------------------------------------------------------------------
// Kernel 4: fp16 MFMA GEMM.  C[b][m] = sum_n X[b][n] * Wt[m][n].
// 128x128 tile, BK=32, 4 waves (2x2), 16x16x32 f16 MFMA, single 16 KB LDS
// buffer, 2 barriers/K-step.  LDS chunk-major: plane[chunk(k/8)][row][8],
// fragment reads lane-contiguous 16B (2-way bank aliasing only; r4: 0 confl).
// ---------------------------------------------------------------------------
__device__ inline void gll16(const void* g, void* l) {
    __builtin_amdgcn_global_load_lds(
        (const __attribute__((address_space(1))) void*)g,
        (__attribute__((address_space(3))) void*)l, 16, 0, 0);
}

__global__ __launch_bounds__(256) void gemm_f16_kernel(const f16* __restrict__ X,
                                                       const f16* __restrict__ Wt,
                                                       float* __restrict__ C) {
    __shared__ f16 As[4096];  // [chunk(4)][row(128)][8] = 8 KB
    __shared__ f16 Bs[4096];

    const int bn0 = blockIdx.x * 128;   // output-col block (Wt row)
    const int bm0 = blockIdx.y * 128;   // batch-row block
    const int t = threadIdx.x;
    const int lane = t & 63;
    const int w = t >> 6;
    const int wm = w >> 1, wn = w & 1;  // 2x2 wave grid, 64x64 per wave
    const int lr = lane & 15;           // fragment row/col
    const int lk = lane >> 4;           // k-chunk 0..3

    f32x4 acc[4][4];
    const f32x4 zero = {0.f, 0.f, 0.f, 0.f};
#pragma unroll
    for (int i = 0; i < 4; ++i)
#pragma unroll
        for (int j = 0; j < 4; ++j) acc[i][j] = zero;

    for (int kt = 0; kt < NT; ++kt) {
        const int k0 = kt * BK;
        __syncthreads();  // prior compute's ds_reads done before overwrite
#pragma unroll
        for (int i = 0; i < 2; ++i) {
            const int f = t + i * 256;  // chunk id 0..511
            const int chunk = f >> 7;   // k-subblock 0..3
            const int row = f & 127;    // tile row
            gll16(X  + (size_t)(bm0 + row) * N + k0 + chunk * 8, (char*)As + f * 16);
            gll16(Wt + (size_t)(bn0 + row) * N + k0 + chunk * 8, (char*)Bs + f * 16);
        }
        __syncthreads();  // stage complete (drains vmcnt)

        half8 a[4], b[4];
#pragma unroll
        for (int q = 0; q < 4; ++q) {
            const int ar = lk * 128 + wm * 64 + q * 16 + lr;  // chunk-major
            const int br = lk * 128 + wn * 64 + q * 16 + lr;
            a[q] = *reinterpret_cast<const half8*>(As + ar * 8);
            b[q] = *reinterpret_cast<const half8*>(Bs + br * 8);
        }
#pragma unroll
        for (int mf = 0; mf < 4; ++mf)
#pragma unroll
            for (int nf = 0; nf < 4; ++nf)
                acc[mf][nf] = __builtin_amdgcn_mfma_f32_16x16x32_f16(a[mf], b[nf], acc[mf][nf], 0, 0, 0);
    }

    // C/D layout (m89-verified, dtype-independent): col=lane&15, row=(lane>>4)*4+reg
#pragma unroll
    for (int mf = 0; mf < 4; ++mf)
#pragma unroll
        for (int nf = 0; nf < 4; ++nf)
#pragma unroll
            for (int r = 0; r < 4; ++r)
                C[(size_t)(bm0 + wm * 64 + mf * 16 + lk * 4 + r) * N +
                  bn0 + wn * 64 + nf * 16 + lr] = acc[mf][nf][r];
}

// ---------------------------------------------------------------------------
// Kernel 5 (fp32 fallback GEMM).
// ---------------------------------------------------------------------------
__global__ __launch_bounds__(256) void gemm_f32_kernel(const float* __restrict__ A,
                                                       const float* __restrict__ B,
                                                       float* __restrict__ C) {
    __shared__ float Asf[16][132];
    __shared__ float Bsf[16][128];

    const int t = threadIdx.x;
    const int bn0 = blockIdx.x * 128;
    const int bm0 = blockIdx.y * 128;
    const int tx = t & 15;
    const int ty = t >> 4;

    float acc[8][8] = {};

    for (int k0 = 0; k0 < N; k0 += 16) {
#pragma unroll
        for (int i = 0; i < 2; ++i) {
            const int flat4 = t + i * 256;
            const int r = flat4 >> 2;
            const int q = flat4 & 3;
            const float4 av =
                *reinterpret_cast<const float4*>(A + (size_t)(bm0 + r) * N + k0 + q * 4);
            Asf[q * 4 + 0][r] = av.x;
            Asf[q * 4 + 1][r] = av.y;
            Asf[q * 4 + 2][r] = av.z;
            Asf[q * 4 + 3][r] = av.w;
            const int rb = flat4 >> 5;
            const int qb = flat4 & 31;
            *reinterpret_cast<float4*>(&Bsf[rb][qb * 4]) =
                *reinterpret_cast<const float4*>(B + (size_t)(k0 + rb) * N + bn0 + qb * 4);
        }
        __syncthreads();
#pragma unroll
        for (int k = 0; k < 16; ++k) {
            float a[8], b[8];
            *reinterpret_cast<float4*>(a)     = *reinterpret_cast<const float4*>(&Asf[k][ty * 8]);
            *reinterpret_cast<float4*>(a + 4) = *reinterpret_cast<const float4*>(&Asf[k][ty * 8 + 4]);
            *reinterpret_cast<float4*>(b)     = *reinterpret_cast<const float4*>(&Bsf[k][tx * 8]);
            *reinterpret_cast<float4*>(b + 4) = *reinterpret_cast<const float4*>(&Bsf[k][tx * 8 + 4]);
#pragma unroll
            for (int e = 0; e < 8; ++e)
#pragma unroll
                for (int f = 0; f < 8; ++f) acc[e][f] += a[e] * b[f];
        }
        __syncthreads();
    }

#pragma unroll
    for (int e = 0; e < 8; ++e) {
        float* crow = C + (size_t)(bm0 + ty * 8 + e) * N + bn0 + tx * 8;
        *reinterpret_cast<float4*>(crow)     = *reinterpret_cast<const float4*>(&acc[0] + e * 8);
        *reinterpret_cast<float4*>(crow + 4) = *reinterpret_cast<const float4*>(&acc[0] + e * 8 + 4);
    }
}

// ---------------------------------------------------------------------------
extern "C" void kernel_launch(void* const* d_in, const int* in_sizes, int n_in,
                              void* d_out, int out_size, void* d_ws, size_t ws_size,
                              hipStream_t stream) {
    const float* x = (const float*)d_in[0];  // (8192, 4096)
    const float* G = (const float*)d_in[1];  // (4096, 4)
    const float* H = (const float*)d_in[2];  // (4096, 4)
    float* out = (float*)d_out;              // (8192, 4096)

    char* ws = (char*)d_ws;
    const size_t SZ_T  = (size_t)N * N * sizeof(float);  // 64 MiB
    const size_t SZ_Wt = (size_t)N * N * 2;              // 32 MiB fp16
    const size_t SZ_X  = (size_t)BATCH * N * 2;          // 64 MiB fp16

    float* T = nullptr;
    f16 *Wt = nullptr, *Xh = nullptr;
    bool f16_path = false;

    if (ws_size >= SZ_T + SZ_Wt + SZ_X) {                // 160 MiB
        T  = (float*)ws;
        Wt = (f16*)(ws + SZ_T);
        Xh = (f16*)(ws + SZ_T + SZ_Wt);
        f16_path = true;
    } else if (ws_size >= SZ_Wt + SZ_X) {                // 96 MiB
        T  = (float*)d_out;  // consumed before the GEMM overwrites d_out
        Wt = (f16*)ws;
        Xh = (f16*)(ws + SZ_Wt);
        f16_path = true;
    }

    if (f16_path) {
        build_T_kernel<<<dim3(N), dim3(256), 0, stream>>>(G, H, T);
        gather_Wt_f16_kernel<<<dim3(N / 64, N / 64), dim3(256), 0, stream>>>(T, Wt);
        cast_x_f16_kernel<<<dim3(2048), dim3(256), 0, stream>>>(x, Xh);
        gemm_f16_kernel<<<dim3(N / 128, BATCH / 128), dim3(256), 0, stream>>>(Xh, Wt, out);
    } else {
        // fp32 fallback: T in d_out (overwritten by GEMM afterwards), W in ws.
        float* Tf = (float*)d_out;
        float* W  = (float*)ws;
        build_T_kernel<<<dim3(N), dim3(256), 0, stream>>>(G, H, Tf);
        gather_W_kernel<<<dim3(N / 64, N / 64), dim3(256), 0, stream>>>(Tf, W);
        gemm_f32_kernel<<<dim3(N / 128, BATCH / 128), dim3(256), 0, stream>>>(x, W, out);
    }
}